// Round 2
// baseline (378.691 us; speedup 1.0000x reference)
//
#include <hip/hip_runtime.h>

// Problem constants (fixed by reference setup_inputs)
#define NB 16
#define NH 32
#define NKH 8
#define NG 4       // H / KH query heads per kv head
#define ND 128
#define NS 8192
#define ATT_SCALE 0.08838834764831845f

// slot_mapping is int64 in the reference; harness docs say ints arrive as
// int32. Sniff the layout (little-endian): if the 8 "high words" of the first
// 8 int64s are all zero, treat as int64 (slots are in [0,8192) so a genuine
// int32 layout has ~0 probability of matching). Reads stay in-bounds for both
// layouts (int32: 64 B, int64: 128 B). Deterministic: input never mutated.
__device__ __forceinline__ int load_slot(const int* __restrict__ sm, int b) {
    bool is64 = true;
#pragma unroll
    for (int i = 0; i < 8; ++i) is64 = is64 && (sm[2 * i + 1] == 0);
    return is64 ? sm[2 * b] : sm[b];
}

// One pure kernel. grid = 256 blocks = 128 (b,kh) pairs x 2 head-halves.
// 1024 threads = 16 waves; each wave handles one cache position per
// iteration for TWO query heads (32-lane halves). K/V float4 addresses are
// identical across halves -> wave coalescer dedups to 512 B/row.
// Sibling blocks (bid, bid+128) share bid%8 -> same XCD L2 for K/V reuse.
__global__ __launch_bounds__(1024, 4) void attn_fused(
    const float* __restrict__ qin, const float* __restrict__ knew,
    const float* __restrict__ vnew, const float* __restrict__ kc,
    const float* __restrict__ vc, const int* __restrict__ slot_map,
    float* __restrict__ out)
{
    const int bid   = blockIdx.x;       // 0..255
    const int pair  = bid & 127;
    const int ghalf = bid >> 7;         // 0,1
    const int kh = pair & 7;
    const int b  = pair >> 3;
    const int tid  = threadIdx.x;
    const int wave = tid >> 6;          // 0..15
    const int lane = tid & 63;
    const int half = lane >> 5;         // which of the 2 heads
    const int il   = lane & 31;
    const int d0   = il * 4;            // 4 d-elements per lane
    const int g    = ghalf * 2 + half;
    const int head = b * NH + kh * NG + g;

    const int slot = load_slot(slot_map, b);

    const float4 qv = *(const float4*)(qin + (size_t)head * ND + d0);
    const float* krow_new = knew + ((size_t)(b * NKH + kh)) * ND + d0;
    const float* vrow_new = vnew + ((size_t)(b * NKH + kh)) * ND + d0;
    const size_t rowstride = (size_t)NKH * ND;           // 1024 floats
    const size_t cbase = ((size_t)b * NS) * rowstride + (size_t)kh * ND + d0;

    float m = -1e30f, l = 0.f;
    float4 acc = make_float4(0.f, 0.f, 0.f, 0.f);

#pragma unroll 2
    for (int s = wave; s < NS; s += 16) {
        const float* kp = (s == slot) ? krow_new : (kc + cbase + (size_t)s * rowstride);
        const float* vp = (s == slot) ? vrow_new : (vc + cbase + (size_t)s * rowstride);
        const float4 kv = *(const float4*)kp;
        const float4 vv = *(const float4*)vp;
        float t = kv.x * qv.x + kv.y * qv.y + kv.z * qv.z + kv.w * qv.w;
        // reduce across the 32-lane half (masks stay within the half)
        t += __shfl_xor(t, 16);
        t += __shfl_xor(t, 8);
        t += __shfl_xor(t, 4);
        t += __shfl_xor(t, 2);
        t += __shfl_xor(t, 1);
        const float sc = t * ATT_SCALE;
        if (sc > m) {   // half-uniform branch, taken ~log2(512) times
            const float corr = __expf(m - sc);   // exp(-1e30) -> 0 first time
            l *= corr;
            acc.x *= corr; acc.y *= corr; acc.z *= corr; acc.w *= corr;
            m = sc;
        }
        const float p = __expf(sc - m);
        l += p;
        acc.x += p * vv.x; acc.y += p * vv.y;
        acc.z += p * vv.z; acc.w += p * vv.w;
    }

    // merge 16 per-wave partials in LDS (16 KiB), wave 0 normalizes+writes
    __shared__ float s_acc[16][64][4];
    __shared__ float s_m[16][2], s_l[16][2];
    *(float4*)&s_acc[wave][lane][0] = acc;
    if (il == 0) { s_m[wave][half] = m; s_l[wave][half] = l; }
    __syncthreads();

    if (wave == 0) {
        float M = -1e30f;
#pragma unroll
        for (int w = 0; w < 16; ++w) M = fmaxf(M, s_m[w][half]);
        float L = 0.f;
        float4 o = make_float4(0.f, 0.f, 0.f, 0.f);
#pragma unroll
        for (int w = 0; w < 16; ++w) {
            const float wg = __expf(s_m[w][half] - M);
            L += wg * s_l[w][half];
            o.x += wg * s_acc[w][lane][0];
            o.y += wg * s_acc[w][lane][1];
            o.z += wg * s_acc[w][lane][2];
            o.w += wg * s_acc[w][lane][3];
        }
        const float inv = 1.f / L;
        float4 r = make_float4(o.x * inv, o.y * inv, o.z * inv, o.w * inv);
        *(float4*)(out + (size_t)head * ND + d0) = r;
    }
}

extern "C" void kernel_launch(void* const* d_in, const int* in_sizes, int n_in,
                              void* d_out, int out_size, void* d_ws, size_t ws_size,
                              hipStream_t stream) {
    const float* q  = (const float*)d_in[0];
    const float* k  = (const float*)d_in[1];
    const float* v  = (const float*)d_in[2];
    const float* kc = (const float*)d_in[3];
    const float* vc = (const float*)d_in[4];
    const int* slot = (const int*)d_in[5];
    float* out = (float*)d_out;
    (void)d_ws; (void)ws_size; (void)in_sizes; (void)n_in; (void)out_size;

    attn_fused<<<dim3(256), dim3(1024), 0, stream>>>(q, k, v, kc, vc, slot, out);
}

// Round 3
// 218.334 us; speedup vs baseline: 1.7345x; 1.7345x over previous
//
#include <hip/hip_runtime.h>

// Problem constants (fixed by reference setup_inputs)
#define NB 16
#define NH 32
#define NKH 8
#define NG 4       // H / KH query heads per kv head
#define ND 128
#define NS 8192
#define ROWF 1024  // NKH*ND floats between consecutive s rows
#define ATT_SCALE 0.08838834764831845f

// slot_mapping is int64 in the reference; harness docs say ints arrive as
// int32. Sniff the layout (little-endian): if the 8 "high words" of the first
// 8 int64s are all zero, treat as int64 (slots are in [0,8192) so a genuine
// int32 layout has ~0 probability of matching). Reads stay in-bounds for both
// layouts (int32: 64 B, int64: 128 B). Input never mutated.
__device__ __forceinline__ int load_slot(const int* __restrict__ sm, int b) {
    bool is64 = true;
#pragma unroll
    for (int i = 0; i < 8; ++i) is64 = is64 && (sm[2 * i + 1] == 0);
    return is64 ? sm[2 * b] : sm[b];
}

// One pure kernel. grid = 256 blocks = 128 (b,kh) pairs x 2 V/output d-halves.
// Block handles ALL 4 query heads of its (b,kh). 1024 threads = 16 waves.
// Within a wave: each 16-lane quarter owns one cache position per iteration
// (4 positions/wave-iter); lane holds 8 K-elements (2 float4) and 4 V-elements
// of the block's d-half. Dot-reduce: 4 shfl levels within the quarter, per g.
// Sibling blocks (bid, bid+128) share bid%8 -> same XCD L2 for the K stream.
__global__ __launch_bounds__(1024, 4) void attn_fused(
    const float* __restrict__ qin, const float* __restrict__ knew,
    const float* __restrict__ vnew, const float* __restrict__ kc,
    const float* __restrict__ vc, const int* __restrict__ slot_map,
    float* __restrict__ out)
{
    const int bid   = blockIdx.x;       // 0..255
    const int pair  = bid & 127;
    const int dhalf = bid >> 7;         // which 64-d half of V/out
    const int kh = pair & 7;
    const int b  = pair >> 3;
    const int tid  = threadIdx.x;
    const int wave = tid >> 6;          // 0..15
    const int lane = tid & 63;
    const int quarter = lane >> 4;      // owns one position per iteration
    const int il   = lane & 15;
    const int dk0  = il * 8;            // K/Q slice: 8 floats
    const int dv0  = dhalf * 64 + il * 4; // V slice: 4 floats

    const int slot = load_slot(slot_map, b);

    // Q fragments for the 4 g heads
    float4 qa[NG], qb[NG];
#pragma unroll
    for (int g = 0; g < NG; ++g) {
        const float* qrow = qin + ((size_t)(b * NH + kh * NG + g)) * ND + dk0;
        qa[g] = *(const float4*)(qrow);
        qb[g] = *(const float4*)(qrow + 4);
    }

    const size_t ck0 = (size_t)b * NS * ROWF + (size_t)kh * ND + dk0;
    const size_t cv0 = (size_t)b * NS * ROWF + (size_t)kh * ND + dv0;
    const float* krow_new = knew + ((size_t)(b * NKH + kh)) * ND + dk0;
    const float* vrow_new = vnew + ((size_t)(b * NKH + kh)) * ND + dv0;

    float m[NG], l[NG];
    float4 acc[NG];
#pragma unroll
    for (int g = 0; g < NG; ++g) {
        m[g] = -1e30f; l[g] = 0.f;
        acc[g] = make_float4(0.f, 0.f, 0.f, 0.f);
    }

    const int sbase = wave * 4 + quarter;   // + i*64
#pragma unroll 2
    for (int i = 0; i < NS / 64; ++i) {
        const int s = sbase + i * 64;
        const float* kp = (s == slot) ? krow_new : (kc + ck0 + (size_t)s * ROWF);
        const float* vp = (s == slot) ? vrow_new : (vc + cv0 + (size_t)s * ROWF);
        const float4 ka = ((const float4*)kp)[0];
        const float4 kb = ((const float4*)kp)[1];
        const float4 vv = *(const float4*)vp;

        float t[NG];
#pragma unroll
        for (int g = 0; g < NG; ++g) {
            t[g] = ka.x * qa[g].x + ka.y * qa[g].y + ka.z * qa[g].z + ka.w * qa[g].w
                 + kb.x * qb[g].x + kb.y * qb[g].y + kb.z * qb[g].z + kb.w * qb[g].w;
        }
        // reduce across the 16-lane quarter (masks stay within the quarter)
#pragma unroll
        for (int g = 0; g < NG; ++g) t[g] += __shfl_xor(t[g], 8);
#pragma unroll
        for (int g = 0; g < NG; ++g) t[g] += __shfl_xor(t[g], 4);
#pragma unroll
        for (int g = 0; g < NG; ++g) t[g] += __shfl_xor(t[g], 2);
#pragma unroll
        for (int g = 0; g < NG; ++g) t[g] += __shfl_xor(t[g], 1);

#pragma unroll
        for (int g = 0; g < NG; ++g) {
            const float sc = t[g] * ATT_SCALE;
            const float mn = fmaxf(m[g], sc);
            const float corr = __expf(m[g] - mn);   // exp(-1e30) -> 0 first iter
            const float p    = __expf(sc - mn);
            m[g] = mn;
            l[g] = l[g] * corr + p;
            acc[g].x = acc[g].x * corr + p * vv.x;
            acc[g].y = acc[g].y * corr + p * vv.y;
            acc[g].z = acc[g].z * corr + p * vv.z;
            acc[g].w = acc[g].w * corr + p * vv.w;
        }
    }

    // ---- cross-quarter merge within the wave (xor 16, 32) ----
#pragma unroll
    for (int g = 0; g < NG; ++g) {
        float M = m[g];
        M = fmaxf(M, __shfl_xor(M, 16));
        M = fmaxf(M, __shfl_xor(M, 32));
        const float w = __expf(m[g] - M);
        float L = l[g] * w;
        L += __shfl_xor(L, 16);
        L += __shfl_xor(L, 32);
        float4 a = make_float4(acc[g].x * w, acc[g].y * w, acc[g].z * w, acc[g].w * w);
        a.x += __shfl_xor(a.x, 16); a.x += __shfl_xor(a.x, 32);
        a.y += __shfl_xor(a.y, 16); a.y += __shfl_xor(a.y, 32);
        a.z += __shfl_xor(a.z, 16); a.z += __shfl_xor(a.z, 32);
        a.w += __shfl_xor(a.w, 16); a.w += __shfl_xor(a.w, 32);
        m[g] = M; l[g] = L; acc[g] = a;
    }

    // ---- merge the 16 wave-partials in LDS ----
    __shared__ float s_acc[16][NG][64];   // 16 KiB
    __shared__ float s_m[16][NG], s_l[16][NG];
    if (quarter == 0) {
#pragma unroll
        for (int g = 0; g < NG; ++g)
            *(float4*)&s_acc[wave][g][il * 4] = acc[g];
        if (il == 0) {
#pragma unroll
            for (int g = 0; g < NG; ++g) { s_m[wave][g] = m[g]; s_l[wave][g] = l[g]; }
        }
    }
    __syncthreads();

    if (tid < NG * 64) {
        const int g  = tid >> 6;
        const int dd = tid & 63;
        float M = -1e30f;
#pragma unroll
        for (int w = 0; w < 16; ++w) M = fmaxf(M, s_m[w][g]);
        float L = 0.f, o = 0.f;
#pragma unroll
        for (int w = 0; w < 16; ++w) {
            const float ww = __expf(s_m[w][g] - M);
            L += ww * s_l[w][g];
            o += ww * s_acc[w][g][dd];
        }
        out[((size_t)(b * NH + kh * NG + g)) * ND + dhalf * 64 + dd] = o / L;
    }
}

extern "C" void kernel_launch(void* const* d_in, const int* in_sizes, int n_in,
                              void* d_out, int out_size, void* d_ws, size_t ws_size,
                              hipStream_t stream) {
    const float* q  = (const float*)d_in[0];
    const float* k  = (const float*)d_in[1];
    const float* v  = (const float*)d_in[2];
    const float* kc = (const float*)d_in[3];
    const float* vc = (const float*)d_in[4];
    const int* slot = (const int*)d_in[5];
    float* out = (float*)d_out;
    (void)d_ws; (void)ws_size; (void)in_sizes; (void)n_in; (void)out_size;

    attn_fused<<<dim3(256), dim3(1024), 0, stream>>>(q, k, v, kc, vc, slot, out);
}